// Round 1
// baseline (90.353 us; speedup 1.0000x reference)
//
#include <hip/hip_runtime.h>

#define N_  8
#define D_  64
#define H_  64
#define W_  64
#define HW_ (H_ * W_)
#define KK  25

// ---------------------------------------------------------------------------
// Kernel 1: per-block nonzero partial counts of cur and prev; ALSO streams
// prev_mem (counted into pr, never consumed) purely to warm L3/L2 for kernel
// 2's pm loads. 512 blocks x 256 threads, 4096 elems/block, 64 blocks per
// batch. Exact partials, no memset, no atomics. (unchanged)
// ---------------------------------------------------------------------------
__global__ __launch_bounds__(256) void count_nz_kernel(
    const float4* __restrict__ cur, const float4* __restrict__ prev,
    const float4* __restrict__ pmv,
    unsigned int* __restrict__ pc, unsigned int* __restrict__ pq,
    unsigned int* __restrict__ pr)
{
    __shared__ unsigned int sc[4], sp[4], sr[4];
    const int t    = threadIdx.x;
    const int wid  = t >> 6;
    const int lane = t & 63;

    unsigned int wc = 0, wp = 0, wr = 0;
#pragma unroll
    for (int j = 0; j < 4; ++j) {
        int idx = blockIdx.x * 1024 + j * 256 + t;
        float4 a = cur[idx];
        float4 b = prev[idx];
        float4 m = pmv[idx];
        wc += (unsigned)__popcll(__ballot(a.x != 0.f));
        wc += (unsigned)__popcll(__ballot(a.y != 0.f));
        wc += (unsigned)__popcll(__ballot(a.z != 0.f));
        wc += (unsigned)__popcll(__ballot(a.w != 0.f));
        wp += (unsigned)__popcll(__ballot(b.x != 0.f));
        wp += (unsigned)__popcll(__ballot(b.y != 0.f));
        wp += (unsigned)__popcll(__ballot(b.z != 0.f));
        wp += (unsigned)__popcll(__ballot(b.w != 0.f));
        wr += (unsigned)__popcll(__ballot(m.x != 0.f));
        wr += (unsigned)__popcll(__ballot(m.y != 0.f));
        wr += (unsigned)__popcll(__ballot(m.z != 0.f));
        wr += (unsigned)__popcll(__ballot(m.w != 0.f));
    }
    if (lane == 0) { sc[wid] = wc; sp[wid] = wp; sr[wid] = wr; }
    __syncthreads();
    if (t == 0) {
        pc[blockIdx.x] = sc[0] + sc[1] + sc[2] + sc[3];
        pq[blockIdx.x] = sp[0] + sp[1] + sp[2] + sp[3];
        pr[blockIdx.x] = sr[0] + sr[1] + sr[2] + sr[3];
    }
}

// ---------------------------------------------------------------------------
// Kernel 2: fused FeatureAlign, float2-vectorized.
// R6 change vs R5 (86.5us): occupancy 2 -> 4 waves/SIMD.
//   - 16 d-groups x 4 channels, 1024 threads/block (was 8 x 8ch, 512 thr).
//     Grid stays 256 (1 block/CU) but waves/CU 8 -> 16. Per-thread load/FMA
//     work halves, so the latency-bound dot & output phases get 2x overlap.
//   - red[] grows to [8][25][128] = 102.4 KB (gfx950 allows >64KB/WG).
//   - XCD swizzle: w=(bid&7)*32+(bid>>3) puts one full batch n on one XCD
//     (3 MB inputs fit the 4 MB per-XCD L2; adjacent y-pair blocks share
//     prev/pm rows within that L2).
// Kept from R5: pm-center + count prefetch before the dot loads; weights on
// first 128 threads; alias-safe in-place weight write.
// ---------------------------------------------------------------------------
__global__ __launch_bounds__(1024, 1) void feature_align_kernel(
    const float* __restrict__ cur, const float* __restrict__ prev,
    const float* __restrict__ pm, float* __restrict__ out,
    const unsigned int* __restrict__ pc, const unsigned int* __restrict__ pq)
{
    __shared__ float red[8][KK][128];   // 102.4 KB; aliased later: red[0]=wght, red[1][0]=zflag

    const int b0   = blockIdx.x;                  // 0..255
    const int b    = ((b0 & 7) << 5) | (b0 >> 3); // XCD-chunk swizzle (bijective, 256%8==0)
    const int n    = b >> 5;                      // batch (== XCD id)
    const int y0   = (b & 31) * 2;                // row pair
    const int lane = threadIdx.x & 63;
    const int dg   = __builtin_amdgcn_readfirstlane(threadIdx.x >> 6); // 0..15
    const int r    = lane >> 5;                   // row within pair
    const int xq   = lane & 31;
    const int x0   = xq * 2;
    const int y    = y0 + r;
    const int pix0 = r * 64 + x0;                 // pixel index in block [0,128)

    // d-invariant per-lane byte offsets.
    int cb[3];
#pragma unroll
    for (int i = 0; i < 3; ++i)
        cb[i] = min(max(x0 - 2 + 2 * i, 0), W_ - 2);     // even -> 8B aligned
    unsigned voff[5][3];
#pragma unroll
    for (int ky = 0; ky < 5; ++ky) {
        int qy = min(max(y + ky - 2, 0), H_ - 1);
#pragma unroll
        for (int i = 0; i < 3; ++i)
            voff[ky][i] = (unsigned)((qy * W_ + cb[i]) * 4);
    }
    const unsigned curoff = (unsigned)((y * W_ + x0) * 4);

    const size_t nbase = (size_t)n * D_ * HW_;
    const char* curb  = (const char*)(cur  + nbase + (size_t)dg * 4 * HW_);
    const char* prevb = (const char*)(prev + nbase + (size_t)dg * 4 * HW_);
    const char* pmb   = (const char*)(pm   + nbase + (size_t)dg * 4 * HW_);
    char*       outb  = (char*)(out + nbase + (size_t)dg * 4 * HW_);

    // ---- EARLY prefetch: pm center values + count partials (off critical path)
    float2 pmc[4];
#pragma unroll
    for (int dd = 0; dd < 4; ++dd)
        pmc[dd] = *(const float2*)(pmb + (size_t)dd * HW_ * 4 + curoff);
    unsigned int ccnt = 0, vcnt = 0;
    if (threadIdx.x < 128) {
        ccnt = pc[(n << 6) + lane];
        vcnt = pq[(n << 6) + lane];
    }

    float acc0[KK], acc1[KK];
#pragma unroll
    for (int k = 0; k < KK; ++k) { acc0[k] = 0.f; acc1[k] = 0.f; }

    // ---- dot-product phase: 4 channels, contiguous float2 loads ----
#pragma unroll
    for (int dd = 0; dd < 4; ++dd) {
        const char* cch = curb  + (size_t)dd * HW_ * 4;
        const char* pch = prevb + (size_t)dd * HW_ * 4;
        float2 c = *(const float2*)(cch + curoff);
        float2 t[5][3];
#pragma unroll
        for (int ky = 0; ky < 5; ++ky)
#pragma unroll
            for (int i = 0; i < 3; ++i)
                t[ky][i] = *(const float2*)(pch + voff[ky][i]);
#pragma unroll
        for (int ky = 0; ky < 5; ++ky) {
            float v[6] = { t[ky][0].x, t[ky][0].y, t[ky][1].x,
                           t[ky][1].y, t[ky][2].x, t[ky][2].y };
#pragma unroll
            for (int kx = 0; kx < 5; ++kx) {
                acc0[ky * 5 + kx] = fmaf(c.x, v[kx],     acc0[ky * 5 + kx]);
                acc1[ky * 5 + kx] = fmaf(c.y, v[kx + 1], acc1[ky * 5 + kx]);
            }
        }
    }

    // ---- cross-dg reduction: dg 0-7 write, dg 8-15 add in place ----
    if (dg < 8) {
#pragma unroll
        for (int k = 0; k < KK; ++k)
            *(float2*)&red[dg][k][pix0] = make_float2(acc0[k], acc1[k]);
    }
    __syncthreads();
    if (dg >= 8) {
#pragma unroll
        for (int k = 0; k < KK; ++k) {
            float2 t2 = *(float2*)&red[dg - 8][k][pix0];
            t2.x += acc0[k]; t2.y += acc1[k];
            *(float2*)&red[dg - 8][k][pix0] = t2;
        }
    }
    __syncthreads();

    // ---- weights: first 128 threads, one pixel each ----
    if (threadIdx.x < 128) {
        const int pix = threadIdx.x;
        const int rr  = pix >> 6;
        const int xx  = pix & 63;

        // counts already in registers; wave-reduce now
        unsigned int cc = ccnt, vv = vcnt;
#pragma unroll
        for (int s = 32; s >= 1; s >>= 1) {
            cc += __shfl_xor(cc, s);
            vv += __shfl_xor(vv, s);
        }
        float scale = 1.0f / (((float)cc + 1e-8f) * ((float)vv + 1e-8f));

        float mass = 0.f;
        float cf[KK];
#pragma unroll
        for (int k = 0; k < KK; ++k) {
            float s = red[0][k][pix] + red[1][k][pix]
                    + red[2][k][pix] + red[3][k][pix]
                    + red[4][k][pix] + red[5][k][pix]
                    + red[6][k][pix] + red[7][k][pix];
            int ky = k / 5, kx = k % 5;
            int py  = y0 + rr + ky - 2;
            int pxc = xx + kx - 2;
            bool val = (py >= 0) && (py < H_) && (pxc >= 0) && (pxc < W_);
            float c = val ? fmaxf(s * scale, 0.f) : 0.f;
            cf[k] = c;
            mass += c;
        }
        bool  zero = fabsf(mass) < 1e-7f;
        float inv  = zero ? 0.f : 1.0f / mass;
        // Alias-safe: this thread read its red[0..7][*][pix] above; only this
        // thread writes column pix. No barrier needed between read and write.
#pragma unroll
        for (int k = 0; k < KK; ++k) red[0][k][pix] = cf[k] * inv;  // wght
        red[1][0][pix] = zero ? 1.f : 0.f;                          // zflag
    }
    __syncthreads();

    // ---- output phase ----
    const float zf0 = red[1][0][pix0];
    const float zf1 = red[1][0][pix0 + 1];

    if (zf0 != 0.f && zf1 != 0.f) {
        // Pure stores of the prefetched pm centers (rare path on this data).
#pragma unroll
        for (int dd = 0; dd < 4; ++dd)
            *(float2*)(outb + (size_t)dd * HW_ * 4 + curoff) = pmc[dd];
    } else {
        float w0[KK], w1[KK];
#pragma unroll
        for (int k = 0; k < KK; ++k) {
            float2 ww = *(float2*)&red[0][k][pix0];
            w0[k] = ww.x; w1[k] = ww.y;
        }
#pragma unroll
        for (int dd = 0; dd < 4; ++dd) {
            const char* pch = pmb + (size_t)dd * HW_ * 4;
            float2 t2[5][3];
#pragma unroll
            for (int ky = 0; ky < 5; ++ky)
#pragma unroll
                for (int i = 0; i < 3; ++i)
                    t2[ky][i] = *(const float2*)(pch + voff[ky][i]);
            float v0 = 0.f, v1 = 0.f;
#pragma unroll
            for (int ky = 0; ky < 5; ++ky) {
                float v[6] = { t2[ky][0].x, t2[ky][0].y, t2[ky][1].x,
                               t2[ky][1].y, t2[ky][2].x, t2[ky][2].y };
#pragma unroll
                for (int kx = 0; kx < 5; ++kx) {
                    v0 = fmaf(w0[ky * 5 + kx], v[kx],     v0);
                    v1 = fmaf(w1[ky * 5 + kx], v[kx + 1], v1);
                }
            }
            float2 o;
            o.x = (zf0 != 0.f) ? pmc[dd].x : v0;
            o.y = (zf1 != 0.f) ? pmc[dd].y : v1;
            *(float2*)(outb + (size_t)dd * HW_ * 4 + curoff) = o;
        }
    }
}

extern "C" void kernel_launch(void* const* d_in, const int* in_sizes, int n_in,
                              void* d_out, int out_size, void* d_ws, size_t ws_size,
                              hipStream_t stream)
{
    const float* cur  = (const float*)d_in[0];
    const float* prev = (const float*)d_in[1];
    const float* pm   = (const float*)d_in[2];
    float*       out  = (float*)d_out;
    unsigned int* pc  = (unsigned int*)d_ws;        // 512 partials (cur)
    unsigned int* pq  = pc + 512;                   // 512 partials (prev)
    unsigned int* pr  = pq + 512;                   // 512 partials (pm, unused)

    count_nz_kernel<<<512, 256, 0, stream>>>(
        (const float4*)cur, (const float4*)prev, (const float4*)pm, pc, pq, pr);

    feature_align_kernel<<<256, 1024, 0, stream>>>(cur, prev, pm, out, pc, pq);
}